// Round 1
// 465.984 us; speedup vs baseline: 1.0895x; 1.0895x over previous
//
#include <hip/hip_runtime.h>

// Problem constants
#define Bsz 16
#define Dch 1024
#define Tsz 1024
#define Hsz 1024
#define Mtot (Bsz*Tsz)   // 16384
#define K2   (2*Dch)     // 2048
#define Ntot (3*Hsz)     // 3072
#define NCH  16          // scan chunks per chain
#define CL   64          // chunk length (NCH*CL == Tsz)
#define NT   32          // K-tiles in GEMM (K2/64)

typedef __attribute__((ext_vector_type(8))) short bf16x8;
typedef __attribute__((ext_vector_type(4))) float f32x4;

__device__ __forceinline__ unsigned short f2bf(float x) {
    unsigned u = __float_as_uint(x);
    u += 0x7FFFu + ((u >> 16) & 1u);   // round-to-nearest-even
    return (unsigned short)(u >> 16);
}
__device__ __forceinline__ float bf2f(unsigned short s) {
    return __uint_as_float(((unsigned)s) << 16);
}

// async global->LDS, 16B per lane, dest = ldsbase + lane*16 (wave-uniform base)
#define GLOAD_LDS16(gp, lp) \
    __builtin_amdgcn_global_load_lds((const __attribute__((address_space(1))) void*)(gp), \
                                     (__attribute__((address_space(3))) void*)(lp), 16, 0, 0)

// Merged prep: blocks [0,4096) build A2 (LDS transpose + causal shift + bf16 pack);
// blocks [4096,5632) cast conv_w fp32->bf16 (flat layout IS B^T row-major already).
__global__ __launch_bounds__(256)
void prep(const float* __restrict__ x, unsigned short* __restrict__ a2,
          const float* __restrict__ w, unsigned short* __restrict__ wb) {
    __shared__ float Xs[64][66];
    int bid = blockIdx.x;
    int tid = threadIdx.x;
    if (bid >= 4096) {
        // prep_w: 1536 blocks * 256 thr * 4 float4 = 1,572,864 float4s
        int i0 = (bid - 4096) * 256 + tid;
        #pragma unroll
        for (int k = 0; k < 4; k++) {
            int i = i0 + k * (1536 * 256);
            float4 v = ((const float4*)w)[i];
            ushort4 r;
            r.x = f2bf(v.x); r.y = f2bf(v.y); r.z = f2bf(v.z); r.w = f2bf(v.w);
            ((ushort4*)wb)[i] = r;
        }
        return;
    }
    int b   = bid >> 8;
    int tt0 = ((bid >> 4) & 15) << 6;
    int dd0 = (bid & 15) << 6;
    int colt = tid & 63, rowq = tid >> 6;
    const size_t xbase = (size_t)b * (Dch * Tsz);
    #pragma unroll
    for (int r = 0; r < 16; r++) {
        int dd = r * 4 + rowq;
        Xs[dd][1 + colt] = x[xbase + (size_t)(dd0 + dd) * Tsz + tt0 + colt];
    }
    if (tid < 64) {
        Xs[tid][0] = (tt0 == 0) ? 0.f : x[xbase + (size_t)(dd0 + tid) * Tsz + tt0 - 1];
    }
    __syncthreads();
    #pragma unroll
    for (int r = 0; r < 16; r++) {
        int tr = r * 4 + rowq;
        int dc = colt;
        float v0 = Xs[dc][tr];       // x[t-1]
        float v1 = Xs[dc][tr + 1];   // x[t]
        unsigned pack = (unsigned)f2bf(v0) | ((unsigned)f2bf(v1) << 16);
        int m = (b << 10) + tt0 + tr;
        ((unsigned*)a2)[(size_t)m * (K2 / 2) + dd0 + dc] = pack;
    }
}

// ===========================================================================
// 256x256-tile, BK=64, 8-wave (2Mx4N) 8-phase GEMM (T2+T3+T4+T5 template).
// LDS: 2 dbuf x (256x64) x {A,B} bf16 = 128 KiB. 1 block/CU, 2 waves/SIMD.
// Chunk swizzle: LDS chunk (row, c) holds global chunk c ^ (row&7); staging
// pre-swizzles the per-lane GLOBAL address (LDS dest stays linear), reads
// XOR the chunk index -> measured 0 bank conflicts with this pattern.
//
// Per K-tile t (4 phases). Read deadlines vs staging overwrites:
//   ph0: ds_read all 8 B-frags + A-frags 0-1 (12);  stage (t+1).A1 (other buf)
//   ph1: ds_read A-frags 2-3 (4);                   stage (t+2).B1 (B read ph0)
//   ph2: ds_read A-frags 4-7 (8);                   stage (t+2).B0 (B read ph0)
//   ph3: no reads;                                  stage (t+2).A0 (A read by ph2)
// Each phase: reads+stage -> barrier -> lgkmcnt(0) -> setprio(1)+16 MFMA -> barrier.
// vmcnt(6) ONCE per tile, before ph3's closing barrier (3 half-tiles in flight),
// so the barrier publishes "tile t+1 landed" to all waves. Tail: vmcnt(0) at t=30.
// ===========================================================================
#define MFMA_PAIR(i0) do { \
    _Pragma("unroll") for (int ks_ = 0; ks_ < 2; ++ks_) { \
      _Pragma("unroll") for (int di_ = 0; di_ < 2; ++di_) { \
        _Pragma("unroll") for (int j_ = 0; j_ < 4; ++j_) { \
          acc[(i0)+di_][j_] = __builtin_amdgcn_mfma_f32_16x16x32_bf16( \
              af[(i0)+di_][ks_], bfr[ks_][j_], acc[(i0)+di_][j_], 0, 0, 0); \
        } } } } while (0)

__global__ __launch_bounds__(512, 2)
void gemm_gates(const unsigned short* __restrict__ A, const unsigned short* __restrict__ Bt,
                const float* __restrict__ bias,
                float* __restrict__ zc, float* __restrict__ fh, unsigned short* __restrict__ ob) {
    __shared__ __align__(16) unsigned short As[2][16384];
    __shared__ __align__(16) unsigned short Bs[2][16384];

    int tid  = threadIdx.x;
    int wv   = tid >> 6, lane = tid & 63;
    int wm   = wv >> 2, wn = wv & 3;        // 2 x 4 waves -> 128x64 per wave
    int lm   = lane & 15, q = lane >> 4;

    // XCD-aware bijective swizzle: 768 wgs = 8 XCDs x 96
    int bid = blockIdx.x;
    int swz = (bid & 7) * 96 + (bid >> 3);
    int mt = swz / 12, nt = swz % 12;       // 64 m-tiles x 12 n-tiles
    int m0 = mt << 8, n0 = nt << 8;

    const unsigned short* Abase = A  + (size_t)m0 * K2;
    const unsigned short* Bbase = Bt + (size_t)n0 * K2;

    // staging constants: lane covers row (wv*8 + l>>3), chunk (l&7); global
    // chunk pre-swizzled by ^(row&7) = ^(l>>3)
    int loff   = (wv * 8 + (lane >> 3)) * K2 + (((lane & 7) ^ (lane >> 3)) << 3);
    int ldsoff = wv * 8 * 64;

    // fragment-read constants (ushort units)
    int sw  = lm & 7;
    int kc0 = (q ^ sw) << 3;          // k-slice 0 -> chunks 0..3
    int kc1 = ((4 + q) ^ sw) << 3;    // k-slice 1 -> chunks 4..7
    int aoff = (wm * 128 + lm) * 64;
    int boff = (wn * 64 + lm) * 64;

    f32x4 acc[8][4] = {};
    bf16x8 af[8][2], bfr[2][4];

#define STAGE_A(t, h) do { \
    const unsigned short* g_ = Abase + (h) * (128 * K2) + (t) * 64 + loff; \
    unsigned short* l_ = &As[(t) & 1][(h) * 8192 + ldsoff]; \
    GLOAD_LDS16(g_, l_); \
    GLOAD_LDS16(g_ + 64 * K2, l_ + 64 * 64); } while (0)
#define STAGE_B(t, h) do { \
    const unsigned short* g_ = Bbase + (h) * (128 * K2) + (t) * 64 + loff; \
    unsigned short* l_ = &Bs[(t) & 1][(h) * 8192 + ldsoff]; \
    GLOAD_LDS16(g_, l_); \
    GLOAD_LDS16(g_ + 64 * K2, l_ + 64 * 64); } while (0)

    // Prologue: tile0 complete + 3 half-tiles of tile1 (tile1.A1 staged in t=0 ph0).
    STAGE_A(0, 0); STAGE_A(0, 1); STAGE_B(0, 0); STAGE_B(0, 1);
    STAGE_B(1, 1); STAGE_B(1, 0); STAGE_A(1, 0);
    asm volatile("s_waitcnt vmcnt(6)" ::: "memory");   // tile0 landed, 6 in flight
    __builtin_amdgcn_s_barrier();

    #pragma unroll 2
    for (int t = 0; t < NT; ++t) {
        const unsigned short* Ab = As[t & 1];
        const unsigned short* Bb = Bs[t & 1];

        // ---------------- phase 0: B all + A 0-1 (12 reads); stage (t+1).A1
        #pragma unroll
        for (int j = 0; j < 4; ++j) {
            bfr[0][j] = *(const bf16x8*)&Bb[boff + j * 1024 + kc0];
            bfr[1][j] = *(const bf16x8*)&Bb[boff + j * 1024 + kc1];
        }
        #pragma unroll
        for (int i = 0; i < 2; ++i) {
            af[i][0] = *(const bf16x8*)&Ab[aoff + i * 1024 + kc0];
            af[i][1] = *(const bf16x8*)&Ab[aoff + i * 1024 + kc1];
        }
        if (t + 1 < NT) STAGE_A(t + 1, 1);
        asm volatile("s_waitcnt lgkmcnt(8)" ::: "memory");
        __builtin_amdgcn_sched_barrier(0);
        __builtin_amdgcn_s_barrier();
        asm volatile("s_waitcnt lgkmcnt(0)" ::: "memory");
        __builtin_amdgcn_sched_barrier(0);
        __builtin_amdgcn_s_setprio(1);
        MFMA_PAIR(0);
        __builtin_amdgcn_s_setprio(0);
        __builtin_amdgcn_sched_barrier(0);
        __builtin_amdgcn_s_barrier();

        // ---------------- phase 1: A 2-3 (4 reads); stage (t+2).B1
        #pragma unroll
        for (int i = 2; i < 4; ++i) {
            af[i][0] = *(const bf16x8*)&Ab[aoff + i * 1024 + kc0];
            af[i][1] = *(const bf16x8*)&Ab[aoff + i * 1024 + kc1];
        }
        if (t + 2 < NT) STAGE_B(t + 2, 1);
        __builtin_amdgcn_sched_barrier(0);
        __builtin_amdgcn_s_barrier();
        asm volatile("s_waitcnt lgkmcnt(0)" ::: "memory");
        __builtin_amdgcn_sched_barrier(0);
        __builtin_amdgcn_s_setprio(1);
        MFMA_PAIR(2);
        __builtin_amdgcn_s_setprio(0);
        __builtin_amdgcn_sched_barrier(0);
        __builtin_amdgcn_s_barrier();

        // ---------------- phase 2: A 4-7 (8 reads); stage (t+2).B0
        #pragma unroll
        for (int i = 4; i < 8; ++i) {
            af[i][0] = *(const bf16x8*)&Ab[aoff + i * 1024 + kc0];
            af[i][1] = *(const bf16x8*)&Ab[aoff + i * 1024 + kc1];
        }
        if (t + 2 < NT) STAGE_B(t + 2, 0);
        __builtin_amdgcn_sched_barrier(0);
        __builtin_amdgcn_s_barrier();
        asm volatile("s_waitcnt lgkmcnt(0)" ::: "memory");
        __builtin_amdgcn_sched_barrier(0);
        __builtin_amdgcn_s_setprio(1);
        MFMA_PAIR(4);
        __builtin_amdgcn_s_setprio(0);
        __builtin_amdgcn_sched_barrier(0);
        __builtin_amdgcn_s_barrier();

        // ---------------- phase 3: no reads; stage (t+2).A0; counted vmcnt
        if (t + 2 < NT) STAGE_A(t + 2, 0);
        __builtin_amdgcn_sched_barrier(0);
        __builtin_amdgcn_s_barrier();
        __builtin_amdgcn_s_setprio(1);
        MFMA_PAIR(6);
        __builtin_amdgcn_s_setprio(0);
        __builtin_amdgcn_sched_barrier(0);
        if (t < NT - 2)       asm volatile("s_waitcnt vmcnt(6)" ::: "memory");
        else if (t == NT - 2) asm volatile("s_waitcnt vmcnt(0)" ::: "memory");
        __builtin_amdgcn_s_barrier();   // publishes: tile t+1 fully landed
    }

    // Epilogue: C/D layout col=lane&15, row=(lane>>4)*4+reg.
    // 256-wide n-tile sits inside one gate (256 | 1024) -> gt block-uniform.
    int gt = nt >> 2;   // 0:z(tanh) 1:f(sigm) 2:o(sigm->bf16)
    #pragma unroll
    for (int i = 0; i < 8; ++i) {
        int mrow = m0 + wm * 128 + i * 16 + q * 4;
        #pragma unroll
        for (int j = 0; j < 4; ++j) {
            int n = n0 + wn * 64 + j * 16 + lm;
            float bv = bias[n];
            int hcol = n & 1023;
            #pragma unroll
            for (int r = 0; r < 4; ++r) {
                float g = acc[i][j][r] + bv;
                size_t idx = (size_t)(mrow + r) * Hsz + hcol;
                if (gt == 0) {
                    float e = __expf(2.f * g);
                    zc[idx] = __fdividef(e - 1.f, e + 1.f);
                } else {
                    float s = __fdividef(1.f, 1.f + __expf(-g));
                    if (gt == 1) fh[idx] = s;
                    else         ob[idx] = f2bf(s);
                }
            }
        }
    }
}

// ---- chunked fo-pooling scan: c_t = z + f*(c - z), c_0 = 0 ----
// Pass 1: per-chunk affine (a = prod f, b = chunk result from c_in=0), 2 chains/thread
__global__ __launch_bounds__(256)
void scan1(const float* __restrict__ zc, const float* __restrict__ fh,
           float* __restrict__ Aw, float* __restrict__ Bw) {
    int blk = blockIdx.x;                 // 16 b * 16 ch * 2 hb = 512
    int hb = blk & 1, ch = (blk >> 1) & 15, b = blk >> 5;
    int h = hb * 512 + threadIdx.x * 2;
    size_t base = ((size_t)b << 20) + ((size_t)(ch * CL) << 10) + h;
    float ax = 1.f, ay = 1.f, bx = 0.f, by = 0.f;
    #pragma unroll 8
    for (int s = 0; s < CL; s++) {
        size_t idx = base + ((size_t)s << 10);
        float2 z = *(const float2*)&zc[idx];
        float2 f = *(const float2*)&fh[idx];
        ax *= f.x; ay *= f.y;
        bx = z.x + f.x * (bx - z.x);
        by = z.y + f.y * (by - z.y);
    }
    int o = (ch * Bsz + b) * Hsz + h;
    *(float2*)&Aw[o] = make_float2(ax, ay);
    *(float2*)&Bw[o] = make_float2(bx, by);
}

// Pass 2 (merged prefix + apply): block computes its own chunk-entry c0 from Aw/Bw
// (block-uniform short loop, L2-hot), then applies the recurrence in place:
// zc: z -> c_seq, fh: f -> h_seq.
__global__ __launch_bounds__(256)
void scan3(float* __restrict__ zc, float* __restrict__ fh,
           const unsigned short* __restrict__ ob,
           const float* __restrict__ Aw, const float* __restrict__ Bw) {
    int blk = blockIdx.x;                 // 512
    int hb = blk & 1, ch = (blk >> 1) & 15, b = blk >> 5;
    int h = hb * 512 + threadIdx.x * 2;
    float cx = 0.f, cy = 0.f;
    for (int cp = 0; cp < ch; cp++) {     // chunk-entry state (block-uniform trip)
        int o = (cp * Bsz + b) * Hsz + h;
        float2 A = *(const float2*)&Aw[o];
        float2 B = *(const float2*)&Bw[o];
        cx = A.x * cx + B.x;
        cy = A.y * cy + B.y;
    }
    size_t base = ((size_t)b << 20) + ((size_t)(ch * CL) << 10) + h;
    #pragma unroll 8
    for (int s = 0; s < CL; s++) {
        size_t idx = base + ((size_t)s << 10);
        float2 z = *(const float2*)&zc[idx];
        float2 f = *(const float2*)&fh[idx];
        unsigned ov = *(const unsigned*)&ob[idx];   // two bf16 o-gates
        cx = z.x + f.x * (cx - z.x);
        cy = z.y + f.y * (cy - z.y);
        *(float2*)&zc[idx] = make_float2(cx, cy);
        float ox = bf2f((unsigned short)(ov & 0xFFFF));
        float oy = bf2f((unsigned short)(ov >> 16));
        *(float2*)&fh[idx] = make_float2(ox * cx, oy * cy);
    }
}

extern "C" void kernel_launch(void* const* d_in, const int* in_sizes, int n_in,
                              void* d_out, int out_size, void* d_ws, size_t ws_size,
                              hipStream_t stream) {
    const float* x    = (const float*)d_in[0];   // [16,1024,1024]
    const float* w    = (const float*)d_in[1];   // [3072,1024,2]
    const float* bias = (const float*)d_in[2];   // [3072]
    float* zc = (float*)d_out;                               // c_seq out (holds z pre-scan)
    float* fh = (float*)d_out + (size_t)Mtot * Hsz;          // h_seq out (holds f pre-scan)
    unsigned short* a2 = (unsigned short*)d_ws;              // 64 MB
    unsigned short* wb = a2 + (size_t)Mtot * K2;             // 12.6 MB
    unsigned short* ob = wb + (size_t)Ntot * K2;             // 32 MB (o gate, bf16)
    float* Aw = (float*)(ob + (size_t)Mtot * Hsz);           // 1 MB
    float* Bw = Aw + NCH * Bsz * Hsz;                        // 1 MB

    hipLaunchKernelGGL(prep, dim3(5632), dim3(256), 0, stream, x, a2, w, wb);
    hipLaunchKernelGGL(gemm_gates, dim3(768), dim3(512), 0, stream, a2, wb, bias, zc, fh, ob);
    hipLaunchKernelGGL(scan1, dim3(512), dim3(256), 0, stream, zc, fh, Aw, Bw);
    hipLaunchKernelGGL(scan3, dim3(512), dim3(256), 0, stream, zc, fh, ob, Aw, Bw);
}

// Round 2
// 464.766 us; speedup vs baseline: 1.0924x; 1.0026x over previous
//
#include <hip/hip_runtime.h>

// Problem constants
#define Bsz 16
#define Dch 1024
#define Tsz 1024
#define Hsz 1024
#define Mtot (Bsz*Tsz)   // 16384
#define K2   (2*Dch)     // 2048
#define Ntot (3*Hsz)     // 3072
#define NCH  16          // scan chunks per chain
#define CL   64          // chunk length (NCH*CL == Tsz)
#define NT   32          // K-tiles in GEMM (K2/64)

typedef __attribute__((ext_vector_type(8))) short bf16x8;
typedef __attribute__((ext_vector_type(4))) float f32x4;

__device__ __forceinline__ unsigned short f2bf(float x) {
    unsigned u = __float_as_uint(x);
    u += 0x7FFFu + ((u >> 16) & 1u);   // round-to-nearest-even
    return (unsigned short)(u >> 16);
}
__device__ __forceinline__ float bf2f(unsigned short s) {
    return __uint_as_float(((unsigned)s) << 16);
}

// async global->LDS, 16B per lane, dest = ldsbase + lane*16 (wave-uniform base)
#define GLOAD_LDS16(gp, lp) \
    __builtin_amdgcn_global_load_lds((const __attribute__((address_space(1))) void*)(gp), \
                                     (__attribute__((address_space(3))) void*)(lp), 16, 0, 0)

// generic LDS pointer -> 32-bit LDS byte offset (for inline-asm ds_read)
#define LDSB(p) ((unsigned)(unsigned long long)(__attribute__((address_space(3))) const void*)(p))

// inline-asm ds_read_b128: invisible to SIInsertWaitcnts, so the compiler
// cannot insert conservative vmcnt waits ordering it vs outstanding
// global_load_lds (LDS-DMA). Data arrival is guaranteed by our manual
// lgkmcnt(0) + sched_barrier(0) before the consuming MFMAs (rule #18).
#define DSR(dst, addr, off) \
    asm volatile("ds_read_b128 %0, %1 offset:" #off : "=v"(dst) : "v"(addr))

// Merged prep: blocks [0,4096) build A2 (LDS transpose + causal shift + bf16 pack);
// blocks [4096,5632) cast conv_w fp32->bf16 (flat layout IS B^T row-major already).
__global__ __launch_bounds__(256)
void prep(const float* __restrict__ x, unsigned short* __restrict__ a2,
          const float* __restrict__ w, unsigned short* __restrict__ wb) {
    __shared__ float Xs[64][66];
    int bid = blockIdx.x;
    int tid = threadIdx.x;
    if (bid >= 4096) {
        // prep_w: 1536 blocks * 256 thr * 4 float4 = 1,572,864 float4s
        int i0 = (bid - 4096) * 256 + tid;
        #pragma unroll
        for (int k = 0; k < 4; k++) {
            int i = i0 + k * (1536 * 256);
            float4 v = ((const float4*)w)[i];
            ushort4 r;
            r.x = f2bf(v.x); r.y = f2bf(v.y); r.z = f2bf(v.z); r.w = f2bf(v.w);
            ((ushort4*)wb)[i] = r;
        }
        return;
    }
    int b   = bid >> 8;
    int tt0 = ((bid >> 4) & 15) << 6;
    int dd0 = (bid & 15) << 6;
    int colt = tid & 63, rowq = tid >> 6;
    const size_t xbase = (size_t)b * (Dch * Tsz);
    #pragma unroll
    for (int r = 0; r < 16; r++) {
        int dd = r * 4 + rowq;
        Xs[dd][1 + colt] = x[xbase + (size_t)(dd0 + dd) * Tsz + tt0 + colt];
    }
    if (tid < 64) {
        Xs[tid][0] = (tt0 == 0) ? 0.f : x[xbase + (size_t)(dd0 + tid) * Tsz + tt0 - 1];
    }
    __syncthreads();
    #pragma unroll
    for (int r = 0; r < 16; r++) {
        int tr = r * 4 + rowq;
        int dc = colt;
        float v0 = Xs[dc][tr];       // x[t-1]
        float v1 = Xs[dc][tr + 1];   // x[t]
        unsigned pack = (unsigned)f2bf(v0) | ((unsigned)f2bf(v1) << 16);
        int m = (b << 10) + tt0 + tr;
        ((unsigned*)a2)[(size_t)m * (K2 / 2) + dd0 + dc] = pack;
    }
}

// ===========================================================================
// 256x256-tile, BK=64, 8-wave (2Mx4N) 8-phase GEMM (T2+T3+T4+T5 template).
// LDS: 2 dbuf x (256x64) x {A,B} bf16 = 128 KiB. 1 block/CU, 2 waves/SIMD.
// Chunk swizzle: LDS chunk (row, c) holds global chunk c ^ (row&7); staging
// pre-swizzles the per-lane GLOBAL address (LDS dest stays linear), reads
// XOR the chunk index -> measured 0 bank conflicts with this pattern.
//
// R2 change: K-loop fragment reads are inline-asm ds_read_b128 (two base
// VGPRs per operand + literal offsets). C-level reads let SIInsertWaitcnts
// see a may-alias vs the outstanding global_load_lds LDS-DMA writes and
// insert conservative vmcnt drains per phase, defeating the counted-vmcnt
// pipeline (T4). asm reads keep only OUR waits.
//
// Per K-tile t (4 phases). Read deadlines vs staging overwrites:
//   ph0: ds_read all 8 B-frags + A-frags 0-1 (12);  stage (t+1).A1 (other buf)
//   ph1: ds_read A-frags 2-3 (4);                   stage (t+2).B1 (B read ph0)
//   ph2: ds_read A-frags 4-7 (8);                   stage (t+2).B0 (B read ph0)
//   ph3: no reads;                                  stage (t+2).A0 (A read by ph2)
// Each phase: reads+stage -> barrier -> lgkmcnt(0) -> setprio(1)+16 MFMA -> barrier.
// vmcnt(6) ONCE per tile, before ph3's closing barrier (3 half-tiles in flight),
// so the barrier publishes "tile t+1 landed" to all waves. Tail: vmcnt(0) at t=30.
// ===========================================================================
#define MFMA_PAIR(i0) do { \
    _Pragma("unroll") for (int ks_ = 0; ks_ < 2; ++ks_) { \
      _Pragma("unroll") for (int di_ = 0; di_ < 2; ++di_) { \
        _Pragma("unroll") for (int j_ = 0; j_ < 4; ++j_) { \
          acc[(i0)+di_][j_] = __builtin_amdgcn_mfma_f32_16x16x32_bf16( \
              af[(i0)+di_][ks_], bfr[ks_][j_], acc[(i0)+di_][j_], 0, 0, 0); \
        } } } } while (0)

__global__ __launch_bounds__(512, 2)
void gemm_gates(const unsigned short* __restrict__ A, const unsigned short* __restrict__ Bt,
                const float* __restrict__ bias,
                float* __restrict__ zc, float* __restrict__ fh, unsigned short* __restrict__ ob) {
    __shared__ __align__(16) unsigned short As[2][16384];
    __shared__ __align__(16) unsigned short Bs[2][16384];

    int tid  = threadIdx.x;
    int wv   = tid >> 6, lane = tid & 63;
    int wm   = wv >> 2, wn = wv & 3;        // 2 x 4 waves -> 128x64 per wave
    int lm   = lane & 15, q = lane >> 4;

    // XCD-aware bijective swizzle: 768 wgs = 8 XCDs x 96
    int bid = blockIdx.x;
    int swz = (bid & 7) * 96 + (bid >> 3);
    int mt = swz / 12, nt = swz % 12;       // 64 m-tiles x 12 n-tiles
    int m0 = mt << 8, n0 = nt << 8;

    const unsigned short* Abase = A  + (size_t)m0 * K2;
    const unsigned short* Bbase = Bt + (size_t)n0 * K2;

    // staging constants: lane covers row (wv*8 + l>>3), chunk (l&7); global
    // chunk pre-swizzled by ^(row&7) = ^(l>>3)
    int loff   = (wv * 8 + (lane >> 3)) * K2 + (((lane & 7) ^ (lane >> 3)) << 3);
    int ldsoff = wv * 8 * 64;

    // fragment-read constants (ushort units)
    int sw  = lm & 7;
    int kc0 = (q ^ sw) << 3;          // k-slice 0 -> chunks 0..3
    int kc1 = ((4 + q) ^ sw) << 3;    // k-slice 1 -> chunks 4..7
    int aoff = (wm * 128 + lm) * 64;
    int boff = (wn * 64 + lm) * 64;

    // LDS byte-offset bases for asm ds_read (k-slice 0/1 each)
    unsigned asb = LDSB(&As[0][0]);
    unsigned bsb = LDSB(&Bs[0][0]);
    unsigned aA0 = asb + (unsigned)(aoff + kc0) * 2u;
    unsigned aA1 = asb + (unsigned)(aoff + kc1) * 2u;
    unsigned aB0 = bsb + (unsigned)(boff + kc0) * 2u;
    unsigned aB1 = bsb + (unsigned)(boff + kc1) * 2u;

    f32x4 acc[8][4] = {};
    bf16x8 af[8][2], bfr[2][4];

#define STAGE_A(t, h) do { \
    const unsigned short* g_ = Abase + (h) * (128 * K2) + (t) * 64 + loff; \
    unsigned short* l_ = &As[(t) & 1][(h) * 8192 + ldsoff]; \
    GLOAD_LDS16(g_, l_); \
    GLOAD_LDS16(g_ + 64 * K2, l_ + 64 * 64); } while (0)
#define STAGE_B(t, h) do { \
    const unsigned short* g_ = Bbase + (h) * (128 * K2) + (t) * 64 + loff; \
    unsigned short* l_ = &Bs[(t) & 1][(h) * 8192 + ldsoff]; \
    GLOAD_LDS16(g_, l_); \
    GLOAD_LDS16(g_ + 64 * K2, l_ + 64 * 64); } while (0)

    // Prologue: tile0 complete + 3 half-tiles of tile1 (tile1.A1 staged in t=0 ph0).
    STAGE_A(0, 0); STAGE_A(0, 1); STAGE_B(0, 0); STAGE_B(0, 1);
    STAGE_B(1, 1); STAGE_B(1, 0); STAGE_A(1, 0);
    asm volatile("s_waitcnt vmcnt(6)" ::: "memory");   // tile0 landed, 6 in flight
    __builtin_amdgcn_s_barrier();

    #pragma unroll 2
    for (int t = 0; t < NT; ++t) {
        unsigned bufo = (t & 1) ? 32768u : 0u;
        unsigned tA0 = aA0 + bufo, tA1 = aA1 + bufo;
        unsigned tB0 = aB0 + bufo, tB1 = aB1 + bufo;

        // ---------------- phase 0: B all + A 0-1 (12 reads); stage (t+1).A1
        DSR(bfr[0][0], tB0, 0);    DSR(bfr[0][1], tB0, 2048);
        DSR(bfr[0][2], tB0, 4096); DSR(bfr[0][3], tB0, 6144);
        DSR(bfr[1][0], tB1, 0);    DSR(bfr[1][1], tB1, 2048);
        DSR(bfr[1][2], tB1, 4096); DSR(bfr[1][3], tB1, 6144);
        DSR(af[0][0], tA0, 0);     DSR(af[0][1], tA1, 0);
        DSR(af[1][0], tA0, 2048);  DSR(af[1][1], tA1, 2048);
        if (t + 1 < NT) STAGE_A(t + 1, 1);
        asm volatile("s_waitcnt lgkmcnt(8)" ::: "memory");
        __builtin_amdgcn_sched_barrier(0);
        __builtin_amdgcn_s_barrier();
        asm volatile("s_waitcnt lgkmcnt(0)" ::: "memory");
        __builtin_amdgcn_sched_barrier(0);
        __builtin_amdgcn_s_setprio(1);
        MFMA_PAIR(0);
        __builtin_amdgcn_s_setprio(0);
        __builtin_amdgcn_sched_barrier(0);
        __builtin_amdgcn_s_barrier();

        // ---------------- phase 1: A 2-3 (4 reads); stage (t+2).B1
        DSR(af[2][0], tA0, 4096);  DSR(af[2][1], tA1, 4096);
        DSR(af[3][0], tA0, 6144);  DSR(af[3][1], tA1, 6144);
        if (t + 2 < NT) STAGE_B(t + 2, 1);
        __builtin_amdgcn_sched_barrier(0);
        __builtin_amdgcn_s_barrier();
        asm volatile("s_waitcnt lgkmcnt(0)" ::: "memory");
        __builtin_amdgcn_sched_barrier(0);
        __builtin_amdgcn_s_setprio(1);
        MFMA_PAIR(2);
        __builtin_amdgcn_s_setprio(0);
        __builtin_amdgcn_sched_barrier(0);
        __builtin_amdgcn_s_barrier();

        // ---------------- phase 2: A 4-7 (8 reads); stage (t+2).B0
        DSR(af[4][0], tA0, 8192);  DSR(af[4][1], tA1, 8192);
        DSR(af[5][0], tA0, 10240); DSR(af[5][1], tA1, 10240);
        DSR(af[6][0], tA0, 12288); DSR(af[6][1], tA1, 12288);
        DSR(af[7][0], tA0, 14336); DSR(af[7][1], tA1, 14336);
        if (t + 2 < NT) STAGE_B(t + 2, 0);
        __builtin_amdgcn_sched_barrier(0);
        __builtin_amdgcn_s_barrier();
        asm volatile("s_waitcnt lgkmcnt(0)" ::: "memory");
        __builtin_amdgcn_sched_barrier(0);
        __builtin_amdgcn_s_setprio(1);
        MFMA_PAIR(4);
        __builtin_amdgcn_s_setprio(0);
        __builtin_amdgcn_sched_barrier(0);
        __builtin_amdgcn_s_barrier();

        // ---------------- phase 3: no reads; stage (t+2).A0; counted vmcnt
        if (t + 2 < NT) STAGE_A(t + 2, 0);
        __builtin_amdgcn_sched_barrier(0);
        __builtin_amdgcn_s_barrier();
        __builtin_amdgcn_s_setprio(1);
        MFMA_PAIR(6);
        __builtin_amdgcn_s_setprio(0);
        __builtin_amdgcn_sched_barrier(0);
        if (t < NT - 2)       asm volatile("s_waitcnt vmcnt(6)" ::: "memory");
        else if (t == NT - 2) asm volatile("s_waitcnt vmcnt(0)" ::: "memory");
        __builtin_amdgcn_s_barrier();   // publishes: tile t+1 fully landed
    }

    // Epilogue: C/D layout col=lane&15, row=(lane>>4)*4+reg.
    // 256-wide n-tile sits inside one gate (256 | 1024) -> gt block-uniform.
    int gt = nt >> 2;   // 0:z(tanh) 1:f(sigm) 2:o(sigm->bf16)
    #pragma unroll
    for (int i = 0; i < 8; ++i) {
        int mrow = m0 + wm * 128 + i * 16 + q * 4;
        #pragma unroll
        for (int j = 0; j < 4; ++j) {
            int n = n0 + wn * 64 + j * 16 + lm;
            float bv = bias[n];
            int hcol = n & 1023;
            #pragma unroll
            for (int r = 0; r < 4; ++r) {
                float g = acc[i][j][r] + bv;
                size_t idx = (size_t)(mrow + r) * Hsz + hcol;
                if (gt == 0) {
                    float e = __expf(2.f * g);
                    zc[idx] = __fdividef(e - 1.f, e + 1.f);
                } else {
                    float s = __fdividef(1.f, 1.f + __expf(-g));
                    if (gt == 1) fh[idx] = s;
                    else         ob[idx] = f2bf(s);
                }
            }
        }
    }
}

// ---- chunked fo-pooling scan: c_t = z + f*(c - z), c_0 = 0 ----
// Pass 1: per-chunk affine (a = prod f, b = chunk result from c_in=0), 2 chains/thread
__global__ __launch_bounds__(256)
void scan1(const float* __restrict__ zc, const float* __restrict__ fh,
           float* __restrict__ Aw, float* __restrict__ Bw) {
    int blk = blockIdx.x;                 // 16 b * 16 ch * 2 hb = 512
    int hb = blk & 1, ch = (blk >> 1) & 15, b = blk >> 5;
    int h = hb * 512 + threadIdx.x * 2;
    size_t base = ((size_t)b << 20) + ((size_t)(ch * CL) << 10) + h;
    float ax = 1.f, ay = 1.f, bx = 0.f, by = 0.f;
    #pragma unroll 8
    for (int s = 0; s < CL; s++) {
        size_t idx = base + ((size_t)s << 10);
        float2 z = *(const float2*)&zc[idx];
        float2 f = *(const float2*)&fh[idx];
        ax *= f.x; ay *= f.y;
        bx = z.x + f.x * (bx - z.x);
        by = z.y + f.y * (by - z.y);
    }
    int o = (ch * Bsz + b) * Hsz + h;
    *(float2*)&Aw[o] = make_float2(ax, ay);
    *(float2*)&Bw[o] = make_float2(bx, by);
}

// Pass 2 (merged prefix + apply): block computes its own chunk-entry c0 from Aw/Bw
// (block-uniform short loop, L2-hot), then applies the recurrence in place:
// zc: z -> c_seq, fh: f -> h_seq.
__global__ __launch_bounds__(256)
void scan3(float* __restrict__ zc, float* __restrict__ fh,
           const unsigned short* __restrict__ ob,
           const float* __restrict__ Aw, const float* __restrict__ Bw) {
    int blk = blockIdx.x;                 // 512
    int hb = blk & 1, ch = (blk >> 1) & 15, b = blk >> 5;
    int h = hb * 512 + threadIdx.x * 2;
    float cx = 0.f, cy = 0.f;
    for (int cp = 0; cp < ch; cp++) {     // chunk-entry state (block-uniform trip)
        int o = (cp * Bsz + b) * Hsz + h;
        float2 A = *(const float2*)&Aw[o];
        float2 B = *(const float2*)&Bw[o];
        cx = A.x * cx + B.x;
        cy = A.y * cy + B.y;
    }
    size_t base = ((size_t)b << 20) + ((size_t)(ch * CL) << 10) + h;
    #pragma unroll 8
    for (int s = 0; s < CL; s++) {
        size_t idx = base + ((size_t)s << 10);
        float2 z = *(const float2*)&zc[idx];
        float2 f = *(const float2*)&fh[idx];
        unsigned ov = *(const unsigned*)&ob[idx];   // two bf16 o-gates
        cx = z.x + f.x * (cx - z.x);
        cy = z.y + f.y * (cy - z.y);
        *(float2*)&zc[idx] = make_float2(cx, cy);
        float ox = bf2f((unsigned short)(ov & 0xFFFF));
        float oy = bf2f((unsigned short)(ov >> 16));
        *(float2*)&fh[idx] = make_float2(ox * cx, oy * cy);
    }
}

extern "C" void kernel_launch(void* const* d_in, const int* in_sizes, int n_in,
                              void* d_out, int out_size, void* d_ws, size_t ws_size,
                              hipStream_t stream) {
    const float* x    = (const float*)d_in[0];   // [16,1024,1024]
    const float* w    = (const float*)d_in[1];   // [3072,1024,2]
    const float* bias = (const float*)d_in[2];   // [3072]
    float* zc = (float*)d_out;                               // c_seq out (holds z pre-scan)
    float* fh = (float*)d_out + (size_t)Mtot * Hsz;          // h_seq out (holds f pre-scan)
    unsigned short* a2 = (unsigned short*)d_ws;              // 64 MB
    unsigned short* wb = a2 + (size_t)Mtot * K2;             // 12.6 MB
    unsigned short* ob = wb + (size_t)Ntot * K2;             // 32 MB (o gate, bf16)
    float* Aw = (float*)(ob + (size_t)Mtot * Hsz);           // 1 MB
    float* Bw = Aw + NCH * Bsz * Hsz;                        // 1 MB

    hipLaunchKernelGGL(prep, dim3(5632), dim3(256), 0, stream, x, a2, w, wb);
    hipLaunchKernelGGL(gemm_gates, dim3(768), dim3(512), 0, stream, a2, wb, bias, zc, fh, ob);
    hipLaunchKernelGGL(scan1, dim3(512), dim3(256), 0, stream, zc, fh, Aw, Bw);
    hipLaunchKernelGGL(scan3, dim3(512), dim3(256), 0, stream, zc, fh, ob, Aw, Bw);
}